// Round 2
// baseline (557.842 us; speedup 1.0000x reference)
//
#include <hip/hip_runtime.h>

typedef unsigned short ushort_t;
typedef unsigned int uint_t;

// Problem constants (from reference)
constexpr int BS_TOTAL = 16 * 32;   // B*S = 512 sentences
constexpr int L = 256;              // seq len
constexpr int D = 768;              // hidden
constexpr int P = 16;               // predicates per sentence
constexpr int T = 4;                // tokens per span
constexpr int PAD = 1;
constexpr int NROWS = 3 * P;        // 48 span rows (pred, arg0, arg1)
constexpr int SPLIT = 8;            // column-parallel splits of the sentence-avg sum
constexpr int C4 = D / 4;           // 192 float4 columns

// ---- workspace layout (bytes) ----
constexpr size_t WS_PART = 0;                                            // float [BS][SPLIT][D]
constexpr size_t WS_NACT = WS_PART + (size_t)BS_TOTAL * SPLIT * D * 4;   // int   [BS]
constexpr size_t WS_ACT  = WS_NACT + (size_t)BS_TOTAL * 4;               // u16   [BS][L]
constexpr size_t WS_N    = WS_ACT  + (size_t)BS_TOTAL * L * 2;           // int   [BS][NROWS]
constexpr size_t WS_DEN  = WS_N    + (size_t)BS_TOTAL * NROWS * 4;       // int   [BS][NROWS]
constexpr size_t WS_ENT  = WS_DEN  + (size_t)BS_TOTAL * NROWS * 4;       // u16   [BS][NROWS][L]
// total ~38.2 MB << ws_size (~1.6 GB)

// ============ kernel 1: per-sentence match metadata ============
__global__ __launch_bounds__(256, 1) void k_meta(
    const int* __restrict__ sent_ids, const int* __restrict__ attn_mask,
    const int* __restrict__ pred_ids, const int* __restrict__ arg0_ids,
    const int* __restrict__ arg1_ids,
    int* __restrict__ ws_nact, ushort_t* __restrict__ ws_act,
    int* __restrict__ ws_n, int* __restrict__ ws_den, ushort_t* __restrict__ ws_ent)
{
    const int bs = blockIdx.x;
    const int t  = threadIdx.x;   // 256 threads, t == l

    __shared__ int      s_span[NROWS * T];
    __shared__ ushort_t s_act[L];
    __shared__ ushort_t s_list[NROWS][L];
    __shared__ int      s_rown[NROWS];
    __shared__ int      s_den[NROWS];
    __shared__ int      s_nact;

    if (t < NROWS) { s_rown[t] = 0; s_den[t] = 0; }
    if (t == 255) s_nact = 0;

    if (t < 64)       s_span[t] = pred_ids[bs * 64 + t];
    else if (t < 128) s_span[t] = arg0_ids[bs * 64 + (t - 64)];
    else if (t < 192) s_span[t] = arg1_ids[bs * 64 + (t - 128)];

    const int sid = sent_ids[bs * L + t];
    const int am  = attn_mask[bs * L + t];
    const int key = (am != 0) ? sid : -1;
    __syncthreads();

    if (key >= 0) {
        const int pos = atomicAdd(&s_nact, 1);
        s_act[pos] = (ushort_t)t;
    }
    for (int r = 0; r < NROWS; ++r) {
        int cnt = 0;
        #pragma unroll
        for (int k = 0; k < T; ++k) {
            const int id = s_span[r * T + k];
            cnt += (id != PAD && id == key) ? 1 : 0;
        }
        if (cnt > 0) {
            const int pos = atomicAdd(&s_rown[r], 1);
            s_list[r][pos] = (ushort_t)((cnt << 8) | t);
            atomicAdd(&s_den[r], cnt);
        }
    }
    __syncthreads();

    if (t == 0) ws_nact[bs] = s_nact;
    ws_act[bs * L + t] = s_act[t];                 // entries >= nact are garbage, never read
    if (t < NROWS) {
        ws_n[bs * NROWS + t]   = s_rown[t];
        ws_den[bs * NROWS + t] = s_den[t];
    }
    for (int r = 0; r < NROWS; ++r) {
        if (t < s_rown[r]) ws_ent[((size_t)bs * NROWS + r) * L + t] = s_list[r][t];
    }
}

// ============ kernel 2a: sentence-average partial sums ============
__global__ __launch_bounds__(192, 1) void k_sent_partial(
    const float* __restrict__ emb, const int* __restrict__ ws_nact,
    const ushort_t* __restrict__ ws_act, float* __restrict__ ws_part)
{
    const int bs = blockIdx.x;
    const int sp = blockIdx.y;
    const int t  = threadIdx.x;   // 192 threads, one float4 column each

    __shared__ ushort_t s_act[L];
    __shared__ int s_n;
    if (t == 0) s_n = ws_nact[bs];
    if (t < L / 2) ((uint_t*)s_act)[t] = ((const uint_t*)(ws_act + bs * L))[t];
    __syncthreads();

    const int nact = s_n;
    const size_t ebase = (size_t)bs * (L * D);
    float4 acc = make_float4(0.f, 0.f, 0.f, 0.f);
    #pragma unroll 4
    for (int i = sp; i < nact; i += SPLIT) {
        const int l = s_act[i];
        const float4 v = *(const float4*)(emb + ebase + (size_t)l * D + 4 * t);
        acc.x += v.x; acc.y += v.y; acc.z += v.z; acc.w += v.w;
    }
    *(float4*)(ws_part + ((size_t)bs * SPLIT + sp) * D + 4 * t) = acc;
}

// ============ kernel 2b: reduce partials, write sentence avg ============
__global__ __launch_bounds__(192, 1) void k_sent_reduce(
    const float* __restrict__ ws_part, const int* __restrict__ ws_nact,
    float* __restrict__ out)
{
    const int bs = blockIdx.x;
    const int t  = threadIdx.x;
    float4 s = make_float4(0.f, 0.f, 0.f, 0.f);
    #pragma unroll
    for (int sp = 0; sp < SPLIT; ++sp) {
        const float4 v = *(const float4*)(ws_part + ((size_t)bs * SPLIT + sp) * D + 4 * t);
        s.x += v.x; s.y += v.y; s.z += v.z; s.w += v.w;
    }
    const int nact = ws_nact[bs];
    const float inv = 1.0f / (float)(nact > 0 ? nact : 1);
    float4 r = make_float4(s.x * inv, s.y * inv, s.z * inv, s.w * inv);
    *(float4*)(out + (size_t)bs * D + 4 * t) = r;
}

// ============ kernel 2c: span-row gathers ============
__global__ __launch_bounds__(192, 1) void k_spans(
    const float* __restrict__ emb, const int* __restrict__ ws_n,
    const int* __restrict__ ws_den, const ushort_t* __restrict__ ws_ent,
    float* __restrict__ out)
{
    const int bs = blockIdx.x;
    const int r  = blockIdx.y;    // 0..47: type = r>>4, p = r&15
    const int t  = threadIdx.x;

    __shared__ ushort_t s_e[L];
    __shared__ int s_n, s_d;
    if (t == 0) { s_n = ws_n[bs * NROWS + r]; s_d = ws_den[bs * NROWS + r]; }
    if (t < L / 2) ((uint_t*)s_e)[t] = ((const uint_t*)(ws_ent + ((size_t)bs * NROWS + r) * L))[t];
    __syncthreads();

    const int n = s_n;
    const size_t ebase = (size_t)bs * (L * D);
    float4 a = make_float4(0.f, 0.f, 0.f, 0.f);
    for (int i = 0; i < n; ++i) {
        const uint_t e = s_e[i];
        const int l = (int)(e & 255u);
        const float w = (float)(e >> 8);
        const float4 v = *(const float4*)(emb + ebase + (size_t)l * D + 4 * t);
        a.x += w * v.x; a.y += w * v.y; a.z += w * v.z; a.w += w * v.w;
    }
    const float inv = (n > 0) ? 1.0f / (float)s_d : 0.0f;
    a.x *= inv; a.y *= inv; a.z *= inv; a.w *= inv;

    const int typ = r >> 4;
    const int p   = r & (P - 1);
    float* op = out + (size_t)BS_TOTAL * D + (size_t)typ * BS_TOTAL * P * D
              + ((size_t)bs * P + p) * D + 4 * t;
    *(float4*)op = a;
}

extern "C" void kernel_launch(void* const* d_in, const int* in_sizes, int n_in,
                              void* d_out, int out_size, void* d_ws, size_t ws_size,
                              hipStream_t stream) {
    const int*   sent = (const int*)d_in[0];
    const int*   attn = (const int*)d_in[1];
    const int*   pred = (const int*)d_in[2];
    const int*   a0   = (const int*)d_in[3];
    const int*   a1   = (const int*)d_in[4];
    const float* emb  = (const float*)d_in[5];
    float*       out  = (float*)d_out;

    char* ws = (char*)d_ws;
    float*    ws_part = (float*)(ws + WS_PART);
    int*      ws_nact = (int*)(ws + WS_NACT);
    ushort_t* ws_act  = (ushort_t*)(ws + WS_ACT);
    int*      ws_n    = (int*)(ws + WS_N);
    int*      ws_den  = (int*)(ws + WS_DEN);
    ushort_t* ws_ent  = (ushort_t*)(ws + WS_ENT);

    k_meta<<<dim3(BS_TOTAL), dim3(256), 0, stream>>>(
        sent, attn, pred, a0, a1, ws_nact, ws_act, ws_n, ws_den, ws_ent);
    k_sent_partial<<<dim3(BS_TOTAL, SPLIT), dim3(C4), 0, stream>>>(
        emb, ws_nact, ws_act, ws_part);
    k_sent_reduce<<<dim3(BS_TOTAL), dim3(C4), 0, stream>>>(
        ws_part, ws_nact, out);
    k_spans<<<dim3(BS_TOTAL, NROWS), dim3(C4), 0, stream>>>(
        emb, ws_n, ws_den, ws_ent, out);
}